// Round 5
// baseline (77.059 us; speedup 1.0000x reference)
//
#include <hip/hip_runtime.h>
#include <cmath>

// Single fused kernel, R=2 rows/thread.
//
// Math: angles = tanh(x@W^T + b); the fixed 3-layer circuit is a constant
// 16x16 unitary U. exps[w] = psi^T M_w psi, M_w = Re(U^dag Z_w U), psi real
// product state => collapses to an 81x4 tensor A contracted with g[9] x h[9].
//
// Structure: 1024 blocks x 256 threads; block covers 512 rows in 2 phases.
// Prep (A in LDS) is recomputed per block, hidden under 2 prefetched rounds
// (~5us of HBM in flight). GEMV reads xt via ds_read_b128 (stride 20).
// Contraction reads A once per 2 rows (b128, uniform broadcast).

#define XADDR(R, P) \
  (x + (row0 + (size_t)((((R) >> 2) * 256) + (P) * 64 + rrow)) * 64 + \
   (size_t)((((R) & 3) * 16) + q4))

#define PREFETCH(RB, R)                                      \
  RB[0] = *reinterpret_cast<const float4*>(XADDR(R, 0));     \
  RB[1] = *reinterpret_cast<const float4*>(XADDR(R, 1));     \
  RB[2] = *reinterpret_cast<const float4*>(XADDR(R, 2));     \
  RB[3] = *reinterpret_cast<const float4*>(XADDR(R, 3));

#define STAGE_WRITE(RB)                                                       \
  *reinterpret_cast<float4*>(&lds[(0 * 64 + rrow) * XS + q4]) = RB[0];        \
  *reinterpret_cast<float4*>(&lds[(1 * 64 + rrow) * XS + q4]) = RB[1];        \
  *reinterpret_cast<float4*>(&lds[(2 * 64 + rrow) * XS + q4]) = RB[2];        \
  *reinterpret_cast<float4*>(&lds[(3 * 64 + rrow) * XS + q4]) = RB[3];

#define GEMV(A0, A1, A2, A3, C) {                                             \
  const float4 xv0 = *reinterpret_cast<const float4*>(&lds[tid * XS + 0]);    \
  const float4 xv1 = *reinterpret_cast<const float4*>(&lds[tid * XS + 4]);    \
  const float4 xv2 = *reinterpret_cast<const float4*>(&lds[tid * XS + 8]);    \
  const float4 xv3 = *reinterpret_cast<const float4*>(&lds[tid * XS + 12]);   \
  const float xr[16] = {xv0.x, xv0.y, xv0.z, xv0.w, xv1.x, xv1.y, xv1.z,      \
                        xv1.w, xv2.x, xv2.y, xv2.z, xv2.w, xv3.x, xv3.y,      \
                        xv3.z, xv3.w};                                        \
  _Pragma("unroll")                                                           \
  for (int f = 0; f < 16; ++f) {                                              \
    A0 = fmaf(xr[f], Wp[(C) * 16 + f], A0);                                   \
    A1 = fmaf(xr[f], Wp[64 + (C) * 16 + f], A1);                              \
    A2 = fmaf(xr[f], Wp[128 + (C) * 16 + f], A2);                             \
    A3 = fmaf(xr[f], Wp[192 + (C) * 16 + f], A3);                             \
  } }

__global__ __launch_bounds__(256, 4) void qfused_kernel(
    const float* __restrict__ x,    // [B][64]
    const float* __restrict__ Wp,   // [4][64]
    const float* __restrict__ bp,   // [4]
    const float* __restrict__ qw,   // [3][4][2]
    float* __restrict__ out)        // [B][4]
{
  constexpr int XS  = 20;           // xt row stride (words); rows 16B-aligned
  constexpr int AOF = 256 * XS;     // 5120
  __shared__ alignas(16) float lds[256 * XS + 324];   // 21.8 KB
  constexpr int SRE = 0;            // prep scratch (inside xt region)
  constexpr int SIM = 272;
  constexpr int MOF = 544;

  const int tid = threadIdx.x;
  const size_t row0 = (size_t)blockIdx.x * 512;
  const int rrow = tid >> 2, q4 = (tid & 3) << 2;

  // ---- prefetch rounds 0,1 (in flight during prep: ~5us of HBM) ----
  float4 rbA[4], rbB[4];
  PREFETCH(rbA, 0);
  PREFETCH(rbB, 1);

  // ---- prep: build A[81][4] at lds[AOF] (256 thr = 16 cols x 16 amps) ----
  {
    const int col = tid >> 4;
    const int u   = tid & 15;
    lds[SRE + col * 17 + u] = (u == col) ? 1.0f : 0.0f;
    lds[SIM + col * 17 + u] = 0.0f;
    __syncthreads();

#pragma unroll
    for (int l = 0; l < 3; ++l) {
#pragma unroll
      for (int w = 0; w < 4; ++w) {
        const int mask = 8 >> w;     // wire 0 = MSB
        float sh, ch, sh2, ch2;
        __sincosf(0.5f * qw[(l * 4 + w) * 2 + 0], &sh, &ch);    // RY
        __sincosf(0.5f * qw[(l * 4 + w) * 2 + 1], &sh2, &ch2);  // RZ
        const int ua = u & ~mask, ub = u | mask;
        const float ar = lds[SRE + col * 17 + ua], ai = lds[SIM + col * 17 + ua];
        const float br = lds[SRE + col * 17 + ub], bi = lds[SIM + col * 17 + ub];
        __syncthreads();
        float nr, ni;
        if (u & mask) { nr = sh * ar + ch * br; ni = sh * ai + ch * bi; }
        else          { nr = ch * ar - sh * br; ni = ch * ai - sh * bi; }
        float rr, ri;
        if (u & mask) { rr = ch2 * nr - sh2 * ni; ri = ch2 * ni + sh2 * nr; }
        else          { rr = ch2 * nr + sh2 * ni; ri = ch2 * ni - sh2 * nr; }
        lds[SRE + col * 17 + u] = rr; lds[SIM + col * 17 + u] = ri;
        __syncthreads();
      }
      // CNOT ring (0,1)(1,2)(2,3)(3,0) as one permutation
      int src = u;
      if (src & 1) src ^= 8;
      if (src & 2) src ^= 1;
      if (src & 4) src ^= 2;
      if (src & 8) src ^= 4;
      const float pr = lds[SRE + col * 17 + src], pi = lds[SIM + col * 17 + src];
      __syncthreads();
      lds[SRE + col * 17 + u] = pr; lds[SIM + col * 17 + u] = pi;
      __syncthreads();
    }

    // M[w][s][t] = sum_u z_w(u) * Re(conj(U[u,s]) U[u,t])
#pragma unroll
    for (int k = 0; k < 4; ++k) {
      const int idx = tid + 256 * k;
      const int w = idx >> 8, s = (idx >> 4) & 15, t = idx & 15;
      const int mask = 8 >> w;
      float acc = 0.0f;
#pragma unroll
      for (int uu = 0; uu < 16; ++uu) {
        const float z = (uu & mask) ? -1.0f : 1.0f;
        acc += z * (lds[SRE + s * 17 + uu] * lds[SRE + t * 17 + uu] +
                    lds[SIM + s * 17 + uu] * lds[SIM + t * 17 + uu]);
      }
      lds[MOF + ((w * 16 + s) * 16 + t)] = acc;
    }
    __syncthreads();

    // A[pq][w]: 16-term sparse Pauli-basis contraction (strided: 324 > 256!)
    for (int idx = tid; idx < 324; idx += 256) {
      const int w = idx & 3, pq = idx >> 2;
      const int p = pq / 9, q = pq % 9;
      const int i0 = p / 3, i1 = p % 3, i2 = q / 3, i3 = q % 3;
      float acc = 0.0f;
#pragma unroll
      for (int comb = 0; comb < 16; ++comb) {
        int s = 0, t = 0;
        float coef = 0.0625f;
        int j;
        j = (comb >> 3) & 1; s |= j << 3; t |= ((i0 == 2) ? (j ^ 1) : j) << 3; if (i0 == 1 && j) coef = -coef;
        j = (comb >> 2) & 1; s |= j << 2; t |= ((i1 == 2) ? (j ^ 1) : j) << 2; if (i1 == 1 && j) coef = -coef;
        j = (comb >> 1) & 1; s |= j << 1; t |= ((i2 == 2) ? (j ^ 1) : j) << 1; if (i2 == 1 && j) coef = -coef;
        j = comb & 1;        s |= j;      t |= ((i3 == 2) ? (j ^ 1) : j);      if (i3 == 1 && j) coef = -coef;
        acc = fmaf(coef, lds[MOF + ((w * 16 + s) * 16 + t)], acc);
      }
      lds[AOF + idx] = acc;
    }
    __syncthreads();   // A ready; prep scratch region now dead
  }

  // ---- 8 rounds (2 phases x 4 feature-chunks), 2-deep ping-pong ----
  float aA0 = 0.f, aA1 = 0.f, aA2 = 0.f, aA3 = 0.f;
  float aB0 = 0.f, aB1 = 0.f, aB2 = 0.f, aB3 = 0.f;

  STAGE_WRITE(rbA); PREFETCH(rbA, 2); __syncthreads();
  GEMV(aA0, aA1, aA2, aA3, 0); __syncthreads();
  STAGE_WRITE(rbB); PREFETCH(rbB, 3); __syncthreads();
  GEMV(aA0, aA1, aA2, aA3, 1); __syncthreads();
  STAGE_WRITE(rbA); PREFETCH(rbA, 4); __syncthreads();
  GEMV(aA0, aA1, aA2, aA3, 2); __syncthreads();
  STAGE_WRITE(rbB); PREFETCH(rbB, 5); __syncthreads();
  GEMV(aA0, aA1, aA2, aA3, 3); __syncthreads();

  // ---- row-A angles -> g0,h0 (frees aA*) ----
  float g0[9], h0[9];
  {
    const float t0 = 1.0f - 2.0f / (__expf(2.0f * (aA0 + bp[0])) + 1.0f);
    const float t1 = 1.0f - 2.0f / (__expf(2.0f * (aA1 + bp[1])) + 1.0f);
    const float t2 = 1.0f - 2.0f / (__expf(2.0f * (aA2 + bp[2])) + 1.0f);
    const float t3 = 1.0f - 2.0f / (__expf(2.0f * (aA3 + bp[3])) + 1.0f);
    float c0, s0, c1, s1, c2, s2, c3, s3;
    __sincosf(t0, &s0, &c0); __sincosf(t1, &s1, &c1);
    __sincosf(t2, &s2, &c2); __sincosf(t3, &s3, &c3);
    g0[0] = 1.f; g0[1] = c1; g0[2] = s1; g0[3] = c0; g0[4] = c0 * c1;
    g0[5] = c0 * s1; g0[6] = s0; g0[7] = s0 * c1; g0[8] = s0 * s1;
    h0[0] = 1.f; h0[1] = c3; h0[2] = s3; h0[3] = c2; h0[4] = c2 * c3;
    h0[5] = c2 * s3; h0[6] = s2; h0[7] = s2 * c3; h0[8] = s2 * s3;
  }

  STAGE_WRITE(rbA); PREFETCH(rbA, 6); __syncthreads();
  GEMV(aB0, aB1, aB2, aB3, 0); __syncthreads();
  STAGE_WRITE(rbB); PREFETCH(rbB, 7); __syncthreads();
  GEMV(aB0, aB1, aB2, aB3, 1); __syncthreads();
  STAGE_WRITE(rbA); __syncthreads();
  GEMV(aB0, aB1, aB2, aB3, 2); __syncthreads();
  STAGE_WRITE(rbB); __syncthreads();
  GEMV(aB0, aB1, aB2, aB3, 3);

  // ---- row-B angles -> g1,h1 ----
  float g1[9], h1[9];
  {
    const float t0 = 1.0f - 2.0f / (__expf(2.0f * (aB0 + bp[0])) + 1.0f);
    const float t1 = 1.0f - 2.0f / (__expf(2.0f * (aB1 + bp[1])) + 1.0f);
    const float t2 = 1.0f - 2.0f / (__expf(2.0f * (aB2 + bp[2])) + 1.0f);
    const float t3 = 1.0f - 2.0f / (__expf(2.0f * (aB3 + bp[3])) + 1.0f);
    float c0, s0, c1, s1, c2, s2, c3, s3;
    __sincosf(t0, &s0, &c0); __sincosf(t1, &s1, &c1);
    __sincosf(t2, &s2, &c2); __sincosf(t3, &s3, &c3);
    g1[0] = 1.f; g1[1] = c1; g1[2] = s1; g1[3] = c0; g1[4] = c0 * c1;
    g1[5] = c0 * s1; g1[6] = s0; g1[7] = s0 * c1; g1[8] = s0 * s1;
    h1[0] = 1.f; h1[1] = c3; h1[2] = s3; h1[3] = c2; h1[4] = c2 * c3;
    h1[5] = c2 * s3; h1[6] = s2; h1[7] = s2 * c3; h1[8] = s2 * s3;
  }

  // ---- contraction: 81 x b128 A-reads shared by both rows ----
  float e00 = 0.f, e01 = 0.f, e02 = 0.f, e03 = 0.f;
  float e10 = 0.f, e11 = 0.f, e12 = 0.f, e13 = 0.f;
#pragma unroll
  for (int p = 0; p < 9; ++p) {
#pragma unroll
    for (int q = 0; q < 9; ++q) {
      const float4 a4 =
          *reinterpret_cast<const float4*>(&lds[AOF + (p * 9 + q) * 4]);
      const float tA = g0[p] * h0[q];
      const float tB = g1[p] * h1[q];
      e00 = fmaf(a4.x, tA, e00); e01 = fmaf(a4.y, tA, e01);
      e02 = fmaf(a4.z, tA, e02); e03 = fmaf(a4.w, tA, e03);
      e10 = fmaf(a4.x, tB, e10); e11 = fmaf(a4.y, tB, e11);
      e12 = fmaf(a4.z, tB, e12); e13 = fmaf(a4.w, tB, e13);
    }
  }
  float4* out4 = reinterpret_cast<float4*>(out);
  out4[row0 + tid]       = make_float4(e00, e01, e02, e03);
  out4[row0 + 256 + tid] = make_float4(e10, e11, e12, e13);
}

extern "C" void kernel_launch(void* const* d_in, const int* in_sizes, int n_in,
                              void* d_out, int out_size, void* d_ws, size_t ws_size,
                              hipStream_t stream) {
  const float* x  = (const float*)d_in[0];
  const float* Wp = (const float*)d_in[1];
  const float* bp = (const float*)d_in[2];
  const float* qw = (const float*)d_in[3];
  float* out = (float*)d_out;
  (void)d_ws; (void)ws_size;

  const int B = in_sizes[0] / 64;   // 524288
  qfused_kernel<<<B / 512, 256, 0, stream>>>(x, Wp, bp, qw, out);
}

// Round 6
// 64.392 us; speedup vs baseline: 1.1967x; 1.1967x over previous
//
#include <hip/hip_runtime.h>
#include <cmath>

// Single fused kernel, 2 adjacent rows per thread, NO LDS staging of x.
//
// Math: angles = tanh(x@W^T + b); fixed 3-layer circuit = constant 16x16
// unitary U; exps collapse to an 81x4 tensor A contracted with g[9] x h[9]
// built from sincos(angles).
//
// Structure: 1024 blocks x 256 threads, all co-resident (4 blk/CU). Each
// block recomputes A in LDS (~2us, concurrent everywhere), one barrier,
// then barrier-free streaming: each thread reads its 2 rows (512 B
// contiguous) straight into registers, GEMV vs wave-uniform W (s_load),
// transcendental tail, contraction vs A (uniform b128 LDS broadcast,
// shared by both rows).
__global__ __launch_bounds__(256, 4) void qfused_kernel(
    const float* __restrict__ x,    // [B][64]
    const float* __restrict__ Wp,   // [4][64]
    const float* __restrict__ bp,   // [4]
    const float* __restrict__ qw,   // [3][4][2]
    float* __restrict__ out)        // [B][4]
{
  // LDS: A[324] (persistent, 16B-aligned at 0) + prep scratch after it.
  constexpr int AOF = 0;     // 324 floats (81 x float4)
  constexpr int SRE = 328;   // 16x17
  constexpr int SIM = 600;   // 16x17
  constexpr int MOF = 872;   // 4x16x16
  __shared__ alignas(16) float lds[872 + 1024];   // 7.6 KB

  const int tid = threadIdx.x;

  // ---- prep: build A[81][4] (256 thr = 16 cols x 16 amplitudes) ----
  {
    const int col = tid >> 4;
    const int u   = tid & 15;
    lds[SRE + col * 17 + u] = (u == col) ? 1.0f : 0.0f;
    lds[SIM + col * 17 + u] = 0.0f;
    __syncthreads();

#pragma unroll
    for (int l = 0; l < 3; ++l) {
#pragma unroll
      for (int w = 0; w < 4; ++w) {
        const int mask = 8 >> w;     // wire 0 = MSB
        float sh, ch, sh2, ch2;
        __sincosf(0.5f * qw[(l * 4 + w) * 2 + 0], &sh, &ch);    // RY
        __sincosf(0.5f * qw[(l * 4 + w) * 2 + 1], &sh2, &ch2);  // RZ
        const int ua = u & ~mask, ub = u | mask;
        const float ar = lds[SRE + col * 17 + ua], ai = lds[SIM + col * 17 + ua];
        const float br = lds[SRE + col * 17 + ub], bi = lds[SIM + col * 17 + ub];
        __syncthreads();
        float nr, ni;
        if (u & mask) { nr = sh * ar + ch * br; ni = sh * ai + ch * bi; }
        else          { nr = ch * ar - sh * br; ni = ch * ai - sh * bi; }
        float rr, ri;
        if (u & mask) { rr = ch2 * nr - sh2 * ni; ri = ch2 * ni + sh2 * nr; }
        else          { rr = ch2 * nr + sh2 * ni; ri = ch2 * ni - sh2 * nr; }
        lds[SRE + col * 17 + u] = rr; lds[SIM + col * 17 + u] = ri;
        __syncthreads();
      }
      // CNOT ring (0,1)(1,2)(2,3)(3,0) as one permutation
      int src = u;
      if (src & 1) src ^= 8;
      if (src & 2) src ^= 1;
      if (src & 4) src ^= 2;
      if (src & 8) src ^= 4;
      const float pr = lds[SRE + col * 17 + src], pi = lds[SIM + col * 17 + src];
      __syncthreads();
      lds[SRE + col * 17 + u] = pr; lds[SIM + col * 17 + u] = pi;
      __syncthreads();
    }

    // M[w][s][t] = sum_u z_w(u) * Re(conj(U[u,s]) U[u,t])
#pragma unroll
    for (int k = 0; k < 4; ++k) {
      const int idx = tid + 256 * k;
      const int w = idx >> 8, s = (idx >> 4) & 15, t = idx & 15;
      const int mask = 8 >> w;
      float acc = 0.0f;
#pragma unroll
      for (int uu = 0; uu < 16; ++uu) {
        const float z = (uu & mask) ? -1.0f : 1.0f;
        acc += z * (lds[SRE + s * 17 + uu] * lds[SRE + t * 17 + uu] +
                    lds[SIM + s * 17 + uu] * lds[SIM + t * 17 + uu]);
      }
      lds[MOF + ((w * 16 + s) * 16 + t)] = acc;
    }
    __syncthreads();

    // A[pq][w]: 16-term sparse Pauli contraction (strided loop: 324 > 256!)
    for (int idx = tid; idx < 324; idx += 256) {
      const int w = idx & 3, pq = idx >> 2;
      const int p = pq / 9, q = pq % 9;
      const int i0 = p / 3, i1 = p % 3, i2 = q / 3, i3 = q % 3;
      float acc = 0.0f;
#pragma unroll
      for (int comb = 0; comb < 16; ++comb) {
        int s = 0, t = 0;
        float coef = 0.0625f;
        int j;
        j = (comb >> 3) & 1; s |= j << 3; t |= ((i0 == 2) ? (j ^ 1) : j) << 3; if (i0 == 1 && j) coef = -coef;
        j = (comb >> 2) & 1; s |= j << 2; t |= ((i1 == 2) ? (j ^ 1) : j) << 2; if (i1 == 1 && j) coef = -coef;
        j = (comb >> 1) & 1; s |= j << 1; t |= ((i2 == 2) ? (j ^ 1) : j) << 1; if (i2 == 1 && j) coef = -coef;
        j = comb & 1;        s |= j;      t |= ((i3 == 2) ? (j ^ 1) : j);      if (i3 == 1 && j) coef = -coef;
        acc = fmaf(coef, lds[MOF + ((w * 16 + s) * 16 + t)], acc);
      }
      lds[AOF + idx] = acc;
    }
    __syncthreads();   // A ready; no barriers after this point
  }

  // ---- streaming: 2 adjacent rows per thread, x -> registers ----
  const size_t rA = ((size_t)blockIdx.x * 256 + (size_t)tid) * 2;
  const float4* xa = reinterpret_cast<const float4*>(x) + rA * 16;

  float a0 = 0.f, a1 = 0.f, a2 = 0.f, a3 = 0.f;   // row A accum
  float b0 = 0.f, b1 = 0.f, b2 = 0.f, b3 = 0.f;   // row B accum
#pragma unroll
  for (int f4 = 0; f4 < 16; ++f4) {
    const float4 va = xa[f4];
    const float4 vb = xa[16 + f4];
    // W reads are wave-uniform constants -> s_load
    const float w00 = Wp[0 * 64 + 4 * f4 + 0], w01 = Wp[0 * 64 + 4 * f4 + 1],
                w02 = Wp[0 * 64 + 4 * f4 + 2], w03 = Wp[0 * 64 + 4 * f4 + 3];
    const float w10 = Wp[1 * 64 + 4 * f4 + 0], w11 = Wp[1 * 64 + 4 * f4 + 1],
                w12 = Wp[1 * 64 + 4 * f4 + 2], w13 = Wp[1 * 64 + 4 * f4 + 3];
    const float w20 = Wp[2 * 64 + 4 * f4 + 0], w21 = Wp[2 * 64 + 4 * f4 + 1],
                w22 = Wp[2 * 64 + 4 * f4 + 2], w23 = Wp[2 * 64 + 4 * f4 + 3];
    const float w30 = Wp[3 * 64 + 4 * f4 + 0], w31 = Wp[3 * 64 + 4 * f4 + 1],
                w32 = Wp[3 * 64 + 4 * f4 + 2], w33 = Wp[3 * 64 + 4 * f4 + 3];
    a0 = fmaf(va.x, w00, a0); a0 = fmaf(va.y, w01, a0);
    a0 = fmaf(va.z, w02, a0); a0 = fmaf(va.w, w03, a0);
    a1 = fmaf(va.x, w10, a1); a1 = fmaf(va.y, w11, a1);
    a1 = fmaf(va.z, w12, a1); a1 = fmaf(va.w, w13, a1);
    a2 = fmaf(va.x, w20, a2); a2 = fmaf(va.y, w21, a2);
    a2 = fmaf(va.z, w22, a2); a2 = fmaf(va.w, w23, a2);
    a3 = fmaf(va.x, w30, a3); a3 = fmaf(va.y, w31, a3);
    a3 = fmaf(va.z, w32, a3); a3 = fmaf(va.w, w33, a3);
    b0 = fmaf(vb.x, w00, b0); b0 = fmaf(vb.y, w01, b0);
    b0 = fmaf(vb.z, w02, b0); b0 = fmaf(vb.w, w03, b0);
    b1 = fmaf(vb.x, w10, b1); b1 = fmaf(vb.y, w11, b1);
    b1 = fmaf(vb.z, w12, b1); b1 = fmaf(vb.w, w13, b1);
    b2 = fmaf(vb.x, w20, b2); b2 = fmaf(vb.y, w21, b2);
    b2 = fmaf(vb.z, w22, b2); b2 = fmaf(vb.w, w23, b2);
    b3 = fmaf(vb.x, w30, b3); b3 = fmaf(vb.y, w31, b3);
    b3 = fmaf(vb.z, w32, b3); b3 = fmaf(vb.w, w33, b3);
  }

  // ---- tail: tanh, sincos, g/h for both rows ----
  // tanh(a) = 1 - 2/(e^{2a}+1)
  float g0[9], h0[9], g1[9], h1[9];
  {
    const float t0 = 1.0f - 2.0f / (__expf(2.0f * (a0 + bp[0])) + 1.0f);
    const float t1 = 1.0f - 2.0f / (__expf(2.0f * (a1 + bp[1])) + 1.0f);
    const float t2 = 1.0f - 2.0f / (__expf(2.0f * (a2 + bp[2])) + 1.0f);
    const float t3 = 1.0f - 2.0f / (__expf(2.0f * (a3 + bp[3])) + 1.0f);
    float c0, s0, c1, s1, c2, s2, c3, s3;
    __sincosf(t0, &s0, &c0); __sincosf(t1, &s1, &c1);
    __sincosf(t2, &s2, &c2); __sincosf(t3, &s3, &c3);
    g0[0] = 1.f; g0[1] = c1; g0[2] = s1; g0[3] = c0; g0[4] = c0 * c1;
    g0[5] = c0 * s1; g0[6] = s0; g0[7] = s0 * c1; g0[8] = s0 * s1;
    h0[0] = 1.f; h0[1] = c3; h0[2] = s3; h0[3] = c2; h0[4] = c2 * c3;
    h0[5] = c2 * s3; h0[6] = s2; h0[7] = s2 * c3; h0[8] = s2 * s3;
  }
  {
    const float t0 = 1.0f - 2.0f / (__expf(2.0f * (b0 + bp[0])) + 1.0f);
    const float t1 = 1.0f - 2.0f / (__expf(2.0f * (b1 + bp[1])) + 1.0f);
    const float t2 = 1.0f - 2.0f / (__expf(2.0f * (b2 + bp[2])) + 1.0f);
    const float t3 = 1.0f - 2.0f / (__expf(2.0f * (b3 + bp[3])) + 1.0f);
    float c0, s0, c1, s1, c2, s2, c3, s3;
    __sincosf(t0, &s0, &c0); __sincosf(t1, &s1, &c1);
    __sincosf(t2, &s2, &c2); __sincosf(t3, &s3, &c3);
    g1[0] = 1.f; g1[1] = c1; g1[2] = s1; g1[3] = c0; g1[4] = c0 * c1;
    g1[5] = c0 * s1; g1[6] = s0; g1[7] = s0 * c1; g1[8] = s0 * s1;
    h1[0] = 1.f; h1[1] = c3; h1[2] = s3; h1[3] = c2; h1[4] = c2 * c3;
    h1[5] = c2 * s3; h1[6] = s2; h1[7] = s2 * c3; h1[8] = s2 * s3;
  }

  // ---- contraction: 81 uniform b128 LDS reads shared by both rows ----
  float e00 = 0.f, e01 = 0.f, e02 = 0.f, e03 = 0.f;
  float e10 = 0.f, e11 = 0.f, e12 = 0.f, e13 = 0.f;
#pragma unroll
  for (int pq = 0; pq < 81; ++pq) {
    const float4 a4 = *reinterpret_cast<const float4*>(&lds[AOF + pq * 4]);
    const float tA = g0[pq / 9] * h0[pq % 9];   // compile-time indices
    const float tB = g1[pq / 9] * h1[pq % 9];
    e00 = fmaf(a4.x, tA, e00); e01 = fmaf(a4.y, tA, e01);
    e02 = fmaf(a4.z, tA, e02); e03 = fmaf(a4.w, tA, e03);
    e10 = fmaf(a4.x, tB, e10); e11 = fmaf(a4.y, tB, e11);
    e12 = fmaf(a4.z, tB, e12); e13 = fmaf(a4.w, tB, e13);
  }
  float4* out4 = reinterpret_cast<float4*>(out);
  out4[rA]     = make_float4(e00, e01, e02, e03);
  out4[rA + 1] = make_float4(e10, e11, e12, e13);
}

extern "C" void kernel_launch(void* const* d_in, const int* in_sizes, int n_in,
                              void* d_out, int out_size, void* d_ws, size_t ws_size,
                              hipStream_t stream) {
  const float* x  = (const float*)d_in[0];
  const float* Wp = (const float*)d_in[1];
  const float* bp = (const float*)d_in[2];
  const float* qw = (const float*)d_in[3];
  float* out = (float*)d_out;
  (void)d_ws; (void)ws_size;

  const int B = in_sizes[0] / 64;   // 524288
  qfused_kernel<<<B / 512, 256, 0, stream>>>(x, Wp, bp, qw, out);
}